// Round 13
// baseline (98.956 us; speedup 1.0000x reference)
//
#include <hip/hip_runtime.h>
#include <hip/hip_bf16.h>

// Match numpy float32 semantics exactly: no FMA contraction, fixed op order.
#pragma clang fp contract(off)

#define B_ 8
#define N_ 4096
#define HALF 2048  // points staged per A-pass (2 passes)
#define C_ 128
#define K_ 16      // SAMPLE (output neighbors)
#define S_ 20      // SAMPLE_NUM (ball_query nsample)
#define NW 8       // queries per block -> 4096 blocks, phase mixing
#define QW 4       // queries per scanning wave (waves 0-1 scan 4 each)
#define NSUB 4     // queries per LDS transpose pass (2 passes)
#define LP 129     // transpose pitch (words): odd -> conflict-light both sides
#define THREADS 512

typedef float f4 __attribute__((ext_vector_type(4)));

// slot s in [0,20) -> output position k = s - 1 - s/5, valid iff s>0 && s%5!=0

__global__ __launch_bounds__(THREADS, 8) void fused_kernel(const float* __restrict__ xyz,
                                                           const float* __restrict__ feat,
                                                           float* __restrict__ out_xyz,
                                                           float* __restrict__ out_feat) {
#pragma clang fp contract(off)
    // ~33 KB union: phase A = packed (x,y,z,sq) half-batch; phase B = transpose
    __shared__ __align__(16) float smem[NSUB * K_ * LP];   // 8256 >= HALF*4=8192
    __shared__ int sidx[NW * K_];
    f4* const pts = reinterpret_cast<f4*>(smem);

    const int w    = blockIdx.x;        // 0..4095
    const int b    = w & 7;             // XCD-align: batch b lives on XCD b
    const int n0   = (w >> 3) * NW;
    const int t    = threadIdx.x;
    const int wave = t >> 6;            // 0..7
    const int lane = t & 63;
    const float* xb = xyz + (size_t)b * (N_ * 3);

    // ---------------- Phase A: waves 0-1 scan 4 queries each, shared reads --
    {
        float qx[QW], qy[QW], qz[QW], sqn[QW];
        int   cnt[QW], first[QW];
        bool  qdone[QW];
        const int myq = wave * QW;           // valid for wave<2
        if (wave < 2) {
#pragma unroll
            for (int qq = 0; qq < QW; ++qq) {
                const int n = n0 + myq + qq;
                qx[qq] = xb[n * 3 + 0];
                qy[qq] = xb[n * 3 + 1];
                qz[qq] = xb[n * 3 + 2];
                sqn[qq] = (qx[qq] * qx[qq] + qy[qq] * qy[qq]) + qz[qq] * qz[qq];
                cnt[qq] = 0; first[qq] = -1; qdone[qq] = false;
            }
        }
        bool alldone = (wave >= 2);          // non-scan waves skip scanning
        const unsigned long long below = (1ull << lane) - 1ull;

        for (int half = 0; half < 2; ++half) {
            __syncthreads();   // prior half's scan reads complete (no-op @ 0)
            // stage packed (x,y,z,sq); sq computed once, exact ref op order
            for (int p = t; p < HALF; p += THREADS) {
                const int gp = half * HALF + p;
                const float x = xb[gp * 3 + 0];
                const float y = xb[gp * 3 + 1];
                const float z = xb[gp * 3 + 2];
                const float sq = (x * x + y * y) + z * z;
                f4 v; v.x = x; v.y = y; v.z = z; v.w = sq;
                pts[p] = v;              // stride-16B across lanes: conflict-free
            }
            __syncthreads();             // half staged

            if (alldone) continue;       // wave-uniform; still hits barriers

            for (int base = 0; base < HALF; base += 256) {
                const int gbase = half * HALF + base;
                f4 P[4];
#pragma unroll
                for (int i = 0; i < 4; ++i)
                    P[i] = pts[base + 64 * i + lane];     // shared by 4 queries

#pragma unroll
                for (int qq = 0; qq < QW; ++qq) {
                    if (qdone[qq]) continue;              // wave-uniform skip
                    bool in[4];
                    unsigned long long M[4];
#pragma unroll
                    for (int i = 0; i < 4; ++i) {
                        const float dt = (qx[qq] * P[i].x + qy[qq] * P[i].y)
                                         + qz[qq] * P[i].z;
                        const float d2 = (sqn[qq] + P[i].w) - 2.0f * dt;
                        in[i] = d2 < 256.0f;
                        M[i]  = __ballot(in[i]);
                    }

                    if (cnt[qq] == 0) {   // wave-uniform: global first hit
                        int f = 0x7fffffff;
#pragma unroll
                        for (int i = 0; i < 4; ++i) {
                            if (M[i]) {
                                const int c = gbase + 64 * i
                                              + (int)__builtin_ctzll(M[i]);
                                f = f < c ? f : c;
                            }
                        }
                        if (f != 0x7fffffff) first[qq] = f;
                    }

                    // in-order slots: cand idx = gbase + 64*i + lane (i-major)
                    int run = cnt[qq];
                    int* out = sidx + (myq + qq) * K_;
#pragma unroll
                    for (int i = 0; i < 4; ++i) {
                        const int s = run + (int)__popcll(M[i] & below);
                        if (in[i] && s > 0 && s < S_ && (s % 5) != 0)
                            out[s - 1 - s / 5] = gbase + 64 * i + lane;
                        run += (int)__popcll(M[i]);
                    }
                    cnt[qq] = run;
                    if (run >= S_) qdone[qq] = true;      // wave-uniform
                }
                alldone = qdone[0] && qdone[1] && qdone[2] && qdone[3];
                if (alldone) break;      // wave-uniform; no barriers inside
            }
        }

        // pad slots [cnt, 20) with 'first'
        if (wave < 2) {
#pragma unroll
            for (int qq = 0; qq < QW; ++qq) {
                int* out = sidx + (myq + qq) * K_;
                if (lane < S_ && lane >= cnt[qq] && lane > 0 && (lane % 5) != 0)
                    out[lane - 1 - lane / 5] = first[qq];
            }
        }
    }
    __syncthreads();   // sidx complete; all scan reads of smem done

    // ---------------- xyz gather (global scattered reads, L2-hot) -----------
    if (t < 3 * NW * K_) {                 // 384 threads
        const int j  = t >> 7;             // 0..2
        const int r  = t & 127;
        const int nl = r >> 4;             // 0..7
        const int k  = r & 15;
        __builtin_nontemporal_store(
            xb[(size_t)sidx[nl * K_ + k] * 3 + j],
            &out_xyz[((size_t)(b * 3 + j) * N_ + (n0 + nl)) * K_ + k]);
    }

    // ---------------- feature gather: 2 sub-tiles, software-pipelined -------
    const float* fb = feat + (size_t)b * N_ * C_;
    float* ob = out_feat + (size_t)b * C_ * N_ * K_ + (size_t)n0 * K_;

    // per-thread tile slice: 4 float4 (rows r = (t+512i)>>5, cols c0 = (t&31)*4)
    f4 v0, v1, v2, v3;
    const int rr0 = t >> 5,        cc0 = (t & 31) * 4;
    const int rr1 = (t + 512) >> 5;
    const int rr2 = (t + 1024) >> 5;
    const int rr3 = (t + 1536) >> 5;

#define LOADREGS(ST)                                                            \
    do {                                                                        \
        const int s_ = (ST) * NSUB;                                             \
        v0 = *reinterpret_cast<const f4*>(                                      \
            fb + (size_t)sidx[(s_ + (rr0 >> 4)) * K_ + (rr0 & 15)] * C_ + cc0); \
        v1 = *reinterpret_cast<const f4*>(                                      \
            fb + (size_t)sidx[(s_ + (rr1 >> 4)) * K_ + (rr1 & 15)] * C_ + cc0); \
        v2 = *reinterpret_cast<const f4*>(                                      \
            fb + (size_t)sidx[(s_ + (rr2 >> 4)) * K_ + (rr2 & 15)] * C_ + cc0); \
        v3 = *reinterpret_cast<const f4*>(                                      \
            fb + (size_t)sidx[(s_ + (rr3 >> 4)) * K_ + (rr3 & 15)] * C_ + cc0); \
    } while (0)

    LOADREGS(0);   // prologue (reads sidx + global only; smem untouched)

    for (int st = 0; st < NW / NSUB; ++st) {
        __syncthreads();   // previous drain (or phase A) done with smem
        // commit tile st from regs into transpose buffer
        smem[rr0 * LP + cc0 + 0] = v0.x; smem[rr0 * LP + cc0 + 1] = v0.y;
        smem[rr0 * LP + cc0 + 2] = v0.z; smem[rr0 * LP + cc0 + 3] = v0.w;
        smem[rr1 * LP + cc0 + 0] = v1.x; smem[rr1 * LP + cc0 + 1] = v1.y;
        smem[rr1 * LP + cc0 + 2] = v1.z; smem[rr1 * LP + cc0 + 3] = v1.w;
        smem[rr2 * LP + cc0 + 0] = v2.x; smem[rr2 * LP + cc0 + 1] = v2.y;
        smem[rr2 * LP + cc0 + 2] = v2.z; smem[rr2 * LP + cc0 + 3] = v2.w;
        smem[rr3 * LP + cc0 + 0] = v3.x; smem[rr3 * LP + cc0 + 1] = v3.y;
        smem[rr3 * LP + cc0 + 2] = v3.z; smem[rr3 * LP + cc0 + 3] = v3.w;

        if (st + 1 < NW / NSUB) LOADREGS(st + 1);   // L2 latency hides under drain

        __syncthreads();
        // drain: nontemporal float4 stores, contiguous 64B per 4 rows;
        // LDS read bank = (r4 + c) % 32 with LP=129 -> ~2-way, free.
        for (int e = t; e < NSUB * K_ * C_ / 4; e += THREADS) {   // 2048 f4
            const int c  = e >> 4;          // 0..127
            const int r4 = (e & 15) * 4;    // 0,4,...,60
            f4 v;
            v.x = smem[(r4 + 0) * LP + c];
            v.y = smem[(r4 + 1) * LP + c];
            v.z = smem[(r4 + 2) * LP + c];
            v.w = smem[(r4 + 3) * LP + c];
            __builtin_nontemporal_store(
                v, reinterpret_cast<f4*>(
                       ob + (size_t)c * (N_ * K_) + (size_t)(st * NSUB) * K_ + r4));
        }
    }
#undef LOADREGS
}

extern "C" void kernel_launch(void* const* d_in, const int* in_sizes, int n_in,
                              void* d_out, int out_size, void* d_ws, size_t ws_size,
                              hipStream_t stream) {
    const float* xyz  = (const float*)d_in[0];   // (8, 4096, 3)
    const float* feat = (const float*)d_in[1];   // (8, 4096, 128)

    float* out_xyz  = (float*)d_out;                       // (8,3,4096,16)
    float* out_feat = out_xyz + (size_t)B_ * 3 * N_ * K_;  // (8,128,4096,16)

    // one block per (b, 8 consecutive queries); fused, no workspace
    hipLaunchKernelGGL(fused_kernel, dim3(B_ * N_ / NW), dim3(THREADS), 0, stream,
                       xyz, feat, out_xyz, out_feat);
}

// Round 14
// 64.549 us; speedup vs baseline: 1.5330x; 1.5330x over previous
//
#include <hip/hip_runtime.h>
#include <hip/hip_bf16.h>

// Match numpy float32 semantics exactly: no FMA contraction, fixed op order.
#pragma clang fp contract(off)

#define B_ 8
#define N_ 4096
#define HALF 2048  // points staged per A-pass (2 passes)
#define C_ 128
#define CH 64      // c's per B-pass (2 passes over c-halves)
#define K_ 16      // SAMPLE (output neighbors)
#define S_ 20      // SAMPLE_NUM (ball_query nsample)
#define NW 8       // queries per block (1 per wave) -> 4096 blocks, phase mixing
#define R_ (NW * K_)   // 128 rows in transpose buffer
#define TP 65      // tbuf row pitch (odd -> stage writes ~2-way)
#define THREADS 512

typedef float f4 __attribute__((ext_vector_type(4)));

// slot s in [0,20) -> output position k = s - 1 - s/5, valid iff s>0 && s%5!=0

__global__ __launch_bounds__(THREADS, 8) void fused_kernel(const float* __restrict__ xyz,
                                                           const float* __restrict__ feat,
                                                           float* __restrict__ out_xyz,
                                                           float* __restrict__ out_feat) {
#pragma clang fp contract(off)
    // ~33 KB union: phase A = packed (x,y,z,sq) half-batch (8192 floats);
    // phase B = transpose buffer [128 r][65 pitch] = 8320 floats
    __shared__ __align__(16) float smem[R_ * TP];
    __shared__ int sidx[NW * K_];
    f4* const pts = reinterpret_cast<f4*>(smem);

    const int w    = blockIdx.x;        // 0..4095
    const int b    = w & 7;             // XCD-align: batch b lives on XCD b
    const int n0   = (w >> 3) * NW;
    const int t    = threadIdx.x;
    const int wave = t >> 6;            // 0..7
    const int lane = t & 63;
    const float* xb = xyz + (size_t)b * (N_ * 3);

    // ---------------- Phase A: 1 query per wave, two staged halves ----------
    // (exact R12 structure -- proven 66 us, bit-exact vs reference)
    {
        const int n  = n0 + wave;
        const float qx = xb[n * 3 + 0];
        const float qy = xb[n * 3 + 1];
        const float qz = xb[n * 3 + 2];
        const float sqn = (qx * qx + qy * qy) + qz * qz;   // exact ref op order

        int cnt = 0;
        int first = -1;
        bool done = false;
        int* out = sidx + wave * K_;
        const unsigned long long below = (1ull << lane) - 1ull;

        for (int half = 0; half < 2; ++half) {
            __syncthreads();   // prior half's scan reads complete (no-op @ 0)
            // stage packed (x,y,z,sq); sq computed once, exact ref op order
            for (int p = t; p < HALF; p += THREADS) {
                const int gp = half * HALF + p;
                const float x = xb[gp * 3 + 0];
                const float y = xb[gp * 3 + 1];
                const float z = xb[gp * 3 + 2];
                const float sq = (x * x + y * y) + z * z;
                f4 v; v.x = x; v.y = y; v.z = z; v.w = sq;
                pts[p] = v;              // stride-16B across lanes: conflict-free
            }
            __syncthreads();             // half staged

            if (done) continue;          // wave-uniform; still hits barriers

            for (int base = 0; base < HALF; base += 512) {
                const int gbase = half * HALF + base;
                bool in[8];
                unsigned long long M[8];
#pragma unroll
                for (int i = 0; i < 8; ++i) {
                    const f4 P = pts[base + 64 * i + lane];   // 1 b128, no conflict
                    const float dt = (qx * P.x + qy * P.y) + qz * P.z;
                    const float d2 = (sqn + P.w) - 2.0f * dt;
                    in[i] = d2 < 256.0f;
                    M[i]  = __ballot(in[i]);
                }

                if (cnt == 0) {   // wave-uniform: global first in-ball index
                    int f = 0x7fffffff;
#pragma unroll
                    for (int i = 0; i < 8; ++i) {
                        if (M[i]) {
                            const int c = gbase + 64 * i + (int)__builtin_ctzll(M[i]);
                            f = f < c ? f : c;
                        }
                    }
                    if (f != 0x7fffffff) first = f;
                }

                // in-order slots: candidate index = gbase + 64*i + lane (i-major)
                int run = cnt;
#pragma unroll
                for (int i = 0; i < 8; ++i) {
                    const int s = run + (int)__popcll(M[i] & below);
                    if (in[i] && s > 0 && s < S_ && (s % 5) != 0)
                        out[s - 1 - s / 5] = gbase + 64 * i + lane;
                    run += (int)__popcll(M[i]);
                }
                cnt = run;
                if (cnt >= S_) { done = true; break; }   // wave-uniform
            }
        }

        // pad slots [cnt, 20) with 'first'
        if (lane < S_ && lane >= cnt && lane > 0 && (lane % 5) != 0) {
            out[lane - 1 - lane / 5] = first;
        }
    }
    __syncthreads();   // sidx complete; all scan reads of smem done

    // ---------------- xyz gather (global scattered reads, L2-hot) -----------
    if (t < 3 * NW * K_) {                 // 384 threads
        const int j  = t >> 7;             // 0..2
        const int r  = t & 127;
        const int nl = r >> 4;             // 0..7
        const int k  = r & 15;
        __builtin_nontemporal_store(
            xb[(size_t)sidx[nl * K_ + k] * 3 + j],
            &out_xyz[((size_t)(b * 3 + j) * N_ + (n0 + nl)) * K_ + k]);
    }

    // ---------------- feature gather: 2 c-half passes, reg-pipelined --------
    // tbuf[r][c] holds ALL 128 rows x 64 c's -> drain emits 512 B contiguous
    // per (c, block) in ONE wave-instruction (vs 2x256 B time-separated).
    const float* fb = feat + (size_t)b * N_ * C_;
    float* ob = out_feat + (size_t)b * C_ * N_ * K_ + (size_t)n0 * K_;

    // per-thread stage slice: 4 f4; f = t + 512*i -> row r = f>>4, cl = (f&15)*4
    f4 v0, v1, v2, v3;
    const int sr0 = t >> 4,            scl = (t & 15) * 4;
    const int sr1 = (t + 512) >> 4;
    const int sr2 = (t + 1024) >> 4;
    const int sr3 = (t + 1536) >> 4;

#define LOADREGS(H)                                                             \
    do {                                                                        \
        const int cg = (H) * CH + scl;                                          \
        v0 = *reinterpret_cast<const f4*>(fb + (size_t)sidx[sr0] * C_ + cg);    \
        v1 = *reinterpret_cast<const f4*>(fb + (size_t)sidx[sr1] * C_ + cg);    \
        v2 = *reinterpret_cast<const f4*>(fb + (size_t)sidx[sr2] * C_ + cg);    \
        v3 = *reinterpret_cast<const f4*>(fb + (size_t)sidx[sr3] * C_ + cg);    \
    } while (0)

    LOADREGS(0);   // prologue (reads sidx + global only; smem untouched)

    for (int h = 0; h < 2; ++h) {
        __syncthreads();   // previous drain (or phase A) done with smem
        // commit pass h from regs into tbuf[r][cl..cl+3]
        smem[sr0 * TP + scl + 0] = v0.x; smem[sr0 * TP + scl + 1] = v0.y;
        smem[sr0 * TP + scl + 2] = v0.z; smem[sr0 * TP + scl + 3] = v0.w;
        smem[sr1 * TP + scl + 0] = v1.x; smem[sr1 * TP + scl + 1] = v1.y;
        smem[sr1 * TP + scl + 2] = v1.z; smem[sr1 * TP + scl + 3] = v1.w;
        smem[sr2 * TP + scl + 0] = v2.x; smem[sr2 * TP + scl + 1] = v2.y;
        smem[sr2 * TP + scl + 2] = v2.z; smem[sr2 * TP + scl + 3] = v2.w;
        smem[sr3 * TP + scl + 0] = v3.x; smem[sr3 * TP + scl + 1] = v3.y;
        smem[sr3 * TP + scl + 2] = v3.z; smem[sr3 * TP + scl + 3] = v3.w;

        if (h == 0) LOADREGS(1);   // L2 latency hides under drain of pass 0

        __syncthreads();
        // drain: e -> cl = e>>5 (0..63), r4 = (e&31)*4; 32 consecutive lanes
        // cover 512 contiguous bytes of one c-stream; nt f4 stores.
        for (int e = t; e < CH * R_ / 4; e += THREADS) {   // 2048 f4
            const int cl = e >> 5;
            const int r4 = (e & 31) * 4;
            f4 v;
            v.x = smem[(r4 + 0) * TP + cl];
            v.y = smem[(r4 + 1) * TP + cl];
            v.z = smem[(r4 + 2) * TP + cl];
            v.w = smem[(r4 + 3) * TP + cl];
            __builtin_nontemporal_store(
                v, reinterpret_cast<f4*>(
                       ob + (size_t)(h * CH + cl) * (N_ * K_) + r4));
        }
    }
#undef LOADREGS
}

extern "C" void kernel_launch(void* const* d_in, const int* in_sizes, int n_in,
                              void* d_out, int out_size, void* d_ws, size_t ws_size,
                              hipStream_t stream) {
    const float* xyz  = (const float*)d_in[0];   // (8, 4096, 3)
    const float* feat = (const float*)d_in[1];   // (8, 4096, 128)

    float* out_xyz  = (float*)d_out;                       // (8,3,4096,16)
    float* out_feat = out_xyz + (size_t)B_ * 3 * N_ * K_;  // (8,128,4096,16)

    // one block per (b, 8 consecutive queries); fused, no workspace
    hipLaunchKernelGGL(fused_kernel, dim3(B_ * N_ / NW), dim3(THREADS), 0, stream,
                       xyz, feat, out_xyz, out_feat);
}